// Round 3
// baseline (448.413 us; speedup 1.0000x reference)
//
#include <hip/hip_runtime.h>
#include <hip/hip_bf16.h>

typedef __attribute__((ext_vector_type(8))) short short8;   // 8 x bf16 = 4 VGPRs
typedef __attribute__((ext_vector_type(4))) short sh4;      // 4 x bf16 = 8 bytes
typedef __attribute__((ext_vector_type(4))) float floatx4;  // MFMA C/D

// total ordering: larger value wins; tie -> smaller index wins (jax.lax.top_k)
__device__ __forceinline__ bool better(float va, int ia, float vb, int ib) {
    return (va > vb) || (va == vb && ia < ib);
}
__device__ __forceinline__ bool betterd(double va, int ia, double vb, int ib) {
    return (va > vb) || (va == vb && ia < ib);
}

__device__ __forceinline__ short bf16_rn(float f) {
    __hip_bfloat16 h = __float2bfloat16(f);   // round-to-nearest-even
    return *reinterpret_cast<short*>(&h);
}
__device__ __forceinline__ float bf16_up(short s) {
    return __uint_as_float(((unsigned)(unsigned short)s) << 16);
}

// split 8 fp32 into bf16 hi + bf16 lo fragments (a ~= hi + lo)
__device__ __forceinline__ void split8(float4 a, float4 b, short8& hi, short8& lo) {
    float v[8] = {a.x, a.y, a.z, a.w, b.x, b.y, b.z, b.w};
    #pragma unroll
    for (int i = 0; i < 8; ++i) {
        short h = bf16_rn(v[i]);
        hi[i] = h;
        lo[i] = bf16_rn(v[i] - bf16_up(h));
    }
}

#define MFMA(A, B, C) __builtin_amdgcn_mfma_f32_16x16x32_bf16((A), (B), (C), 0, 0, 0)

// async global -> LDS, 16B per lane.  LDS dest = wave-uniform base + lane*16.
__device__ __forceinline__ void gload16(const void* g, void* l) {
    __builtin_amdgcn_global_load_lds(
        (const __attribute__((address_space(1))) void*)g,
        (__attribute__((address_space(3))) void*)l,
        16, 0, 0);
}

// ---------------------------------------------------------------------------
// Prep: split W (64x1024 fp32) into bf16 hi/lo, PERMUTED so router staging and
// reads are both linear-in-lane.  Granule = 8 bf16 (16B).  Layout:
//   whi[c][g][q][e] : chunk c (32 k-floats), expert group g (experts 16g+e),
//                     k-octet q (k = 32c + 8q .. +7), e in 0..15.
//   idx = c*256 + g*64 + q*16 + e   (8192 granules, 128 KB per half)
// Values identical to split8() on the fly -> main-path numerics unchanged.
// ---------------------------------------------------------------------------
__global__ __launch_bounds__(256)
void wsplit_kernel(const float* __restrict__ Wg,
                   short* __restrict__ whi,
                   short* __restrict__ wlo)
{
    const int idx = blockIdx.x * 256 + threadIdx.x;   // 32 blocks -> 8192 granules
    const int c = idx >> 8;
    const int g = (idx >> 6) & 3;
    const int q = (idx >> 4) & 3;
    const int e = idx & 15;
    const float* src = Wg + (size_t)(g * 16 + e) * 1024 + c * 32 + q * 8;
    float4 v0 = reinterpret_cast<const float4*>(src)[0];
    float4 v1 = reinterpret_cast<const float4*>(src)[1];
    short8 hi, lo;
    split8(v0, v1, hi, lo);
    reinterpret_cast<short8*>(whi)[idx] = hi;
    reinterpret_cast<short8*>(wlo)[idx] = lo;
}

// ---------------------------------------------------------------------------
// Main router: async double-buffered LDS pipeline, conflict-free layout.
//   chunk = 32 k-floats.  Buffer 16 KB = [A: 4 waves x 2KB | Whi 4KB | Wlo 4KB].
//   A wave block = [j in 2][q in 4][r in 16] granules -> a0/a1 reads are
//   contiguous 1KB per wave.  W = [g][q][e] granules -> each h_g/l_g read is a
//   contiguous 1KB wave read.  ALL LDS reads are base + lane*16: zero bank
//   conflicts, zero swizzle arithmetic.
//   2 buffers = 32 KB total (gtile aliased onto stage after the k-loop)
//   -> 4 blocks/CU resident (grid-limited), 16 waves/CU.
//   Per chunk per wave: 4 global_load_lds; counted vmcnt(4) keeps next chunk's
//   loads in flight across the barrier (never drain mid-loop).
// Numerics bitwise identical to previous rounds: same splits, same MFMA order.
// ---------------------------------------------------------------------------
__global__ __launch_bounds__(256, 4)
void router_kernel(const float* __restrict__ tokens,
                   const int* __restrict__ tarr,
                   const float* __restrict__ bg,
                   float* __restrict__ out,
                   int* __restrict__ flagCount,
                   int* __restrict__ flagList,
                   int listCap,
                   const short* __restrict__ whi,
                   const short* __restrict__ wlo)
{
    __shared__ __align__(16) char smem[32768];       // 2 x 16KB stage; gtile alias
    const int WH_OFF = 8192, WL_OFF = 12288;

    const int lane = threadIdx.x & 63;
    const int wave = threadIdx.x >> 6;
    const int c16  = lane & 15;   // token-within-wave (A row) / expert-within-group
    const int quad = lane >> 4;   // k-octet selector

    const int tokenBase = blockIdx.x * 64;

    // staging sources (chunk 0); advance by immediate per chunk
    //   A: staging lane l fetches granule (r=l&15, q=l>>4, j) of its wave's rows
    const char* aS0 = (const char*)tokens
        + (size_t)(tokenBase + wave * 16 + c16) * 4096 + quad * 32;   // j=0 plane
    //   W: global layout already matches LDS order -> contiguous 1KB per wave
    const char* hS = (const char*)whi + wave * 1024 + (size_t)lane * 16;
    const char* lS = (const char*)wlo + wave * 1024 + (size_t)lane * 16;

    floatx4 acc0 = {0.f, 0.f, 0.f, 0.f};
    floatx4 acc1 = acc0, acc2 = acc0, acc3 = acc0;

    const int aRd = wave * 2048 + lane * 16;   // this lane's A read offset
    const int wRd = lane * 16;                 // this lane's W read offset

    // ---- stage chunk 0 into buffer 0 -------------------------------------
    {
        char* b = smem;
        gload16(aS0,      b + wave * 2048);          // j=0 plane (1KB/wave)
        gload16(aS0 + 16, b + wave * 2048 + 1024);   // j=1 plane
        gload16(hS, b + WH_OFF + wave * 1024);       // Whi group g=wave
        gload16(lS, b + WL_OFF + wave * 1024);       // Wlo group g=wave
    }

    for (int c = 0; c < 32; ++c) {
        char* cur = smem + (c & 1) * 16384;
        char* nxt = smem + ((c & 1) ^ 1) * 16384;

        // ---- stage chunk c+1 (async, stays in flight across the barrier) --
        if (c < 31) {
            const int co = (c + 1) * 128;    // A bytes per chunk
            const int cw = (c + 1) * 4096;   // W bytes per chunk
            gload16(aS0 + co,      nxt + wave * 2048);
            gload16(aS0 + co + 16, nxt + wave * 2048 + 1024);
            gload16(hS + cw, nxt + WH_OFF + wave * 1024);
            gload16(lS + cw, nxt + WL_OFF + wave * 1024);
            asm volatile("s_waitcnt vmcnt(4)" ::: "memory");   // chunk c landed
        } else {
            asm volatile("s_waitcnt vmcnt(0)" ::: "memory");   // last chunk: drain
        }
        __builtin_amdgcn_s_barrier();
        asm volatile("" ::: "memory");

        // ---- compute chunk c: all LDS reads are contiguous per wave --------
        float4 a0 = *(const float4*)(cur + aRd);
        float4 a1 = *(const float4*)(cur + aRd + 1024);
        short8 h0 = *(const short8*)(cur + WH_OFF +    0 + wRd);
        short8 h1 = *(const short8*)(cur + WH_OFF + 1024 + wRd);
        short8 h2 = *(const short8*)(cur + WH_OFF + 2048 + wRd);
        short8 h3 = *(const short8*)(cur + WH_OFF + 3072 + wRd);
        short8 l0 = *(const short8*)(cur + WL_OFF +    0 + wRd);
        short8 l1 = *(const short8*)(cur + WL_OFF + 1024 + wRd);
        short8 l2 = *(const short8*)(cur + WL_OFF + 2048 + wRd);
        short8 l3 = *(const short8*)(cur + WL_OFF + 3072 + wRd);

        short8 ahi, alo;
        split8(a0, a1, ahi, alo);

        // same per-acc MFMA order as before -> bitwise-identical accumulation
        acc0 = MFMA(ahi, h0, acc0); acc0 = MFMA(alo, h0, acc0); acc0 = MFMA(ahi, l0, acc0);
        acc1 = MFMA(ahi, h1, acc1); acc1 = MFMA(alo, h1, acc1); acc1 = MFMA(ahi, l1, acc1);
        acc2 = MFMA(ahi, h2, acc2); acc2 = MFMA(alo, h2, acc2); acc2 = MFMA(ahi, l2, acc2);
        acc3 = MFMA(ahi, h3, acc3); acc3 = MFMA(alo, h3, acc3); acc3 = MFMA(ahi, l3, acc3);

        __builtin_amdgcn_s_barrier();     // all waves done reading cur before restage
        asm volatile("" ::: "memory");
    }

    __syncthreads();   // full fence before aliasing smem as the gate tile

    float* gtile = reinterpret_cast<float*>(smem);   // 16 KB alias (safe post-loop)

    const float b0f = bg[c16 +  0];
    const float b1f = bg[c16 + 16];
    const float b2f = bg[c16 + 32];
    const float b3f = bg[c16 + 48];

    const float tb  = (float)tarr[tokenBase >> 12];   // 4096 tokens per batch
    const float cap = 0.5f + 1.1f * (tb / 1000.0f);

    const float A1 = 0.85f;            // 1 - alpha, alpha = 0.15
    const float A2 = 0.15f / 64.0f;    // alpha / E

    #pragma unroll
    for (int rr = 0; rr < 4; ++rr) {
        float l0 = acc0[rr] + b0f;
        float l1 = acc1[rr] + b1f;
        float l2 = acc2[rr] + b2f;
        float l3 = acc3[rr] + b3f;

        // --- softmax over 64 experts (16-lane group x 4 local) ---
        float mx = fmaxf(fmaxf(l0, l1), fmaxf(l2, l3));
        #pragma unroll
        for (int off = 8; off >= 1; off >>= 1)
            mx = fmaxf(mx, __shfl_xor(mx, off));

        float e0 = expf(l0 - mx), e1 = expf(l1 - mx);
        float e2 = expf(l2 - mx), e3 = expf(l3 - mx);
        float s = e0 + e1 + e2 + e3;
        #pragma unroll
        for (int off = 8; off >= 1; off >>= 1)
            s += __shfl_xor(s, off);
        float inv = 1.0f / s;

        // --- routing floor ---
        float p0 = A1 * (e0 * inv) + A2;
        float p1 = A1 * (e1 * inv) + A2;
        float p2 = A1 * (e2 * inv) + A2;
        float p3 = A1 * (e3 * inv) + A2;

        // --- hard cap with excess redistribution ---
        float x0 = fmaxf(p0 - cap, 0.f), x1 = fmaxf(p1 - cap, 0.f);
        float x2 = fmaxf(p2 - cap, 0.f), x3 = fmaxf(p3 - cap, 0.f);
        float m0 = p0 - x0, m1 = p1 - x1, m2 = p2 - x2, m3 = p3 - x3;
        float h0 = fmaxf(cap - m0, 0.f), h1 = fmaxf(cap - m1, 0.f);
        float h2 = fmaxf(cap - m2, 0.f), h3 = fmaxf(cap - m3, 0.f);
        float sx = x0 + x1 + x2 + x3;
        float sh = h0 + h1 + h2 + h3;
        #pragma unroll
        for (int off = 8; off >= 1; off >>= 1) {
            sx += __shfl_xor(sx, off);
            sh += __shfl_xor(sh, off);
        }
        sh = fmaxf(sh, 1e-8f);
        float sc = sx / sh;
        float c0 = m0 + sc * h0;
        float c1 = m1 + sc * h1;
        float c2 = m2 + sc * h2;
        float c3 = m3 + sc * h3;

        // --- top-2 (value desc, tie -> smaller expert index) ---
        const int iA = c16, iB = c16 + 16, iC = c16 + 32, iD = c16 + 48;
        float v1, v2; int j1, j2;
        if (better(c0, iA, c1, iB)) { v1 = c0; j1 = iA; v2 = c1; j2 = iB; }
        else                        { v1 = c1; j1 = iB; v2 = c0; j2 = iA; }
        if (better(c2, iC, v1, j1))      { v2 = v1; j2 = j1; v1 = c2; j1 = iC; }
        else if (better(c2, iC, v2, j2)) { v2 = c2; j2 = iC; }
        if (better(c3, iD, v1, j1))      { v2 = v1; j2 = j1; v1 = c3; j1 = iD; }
        else if (better(c3, iD, v2, j2)) { v2 = c3; j2 = iD; }

        #pragma unroll
        for (int off = 1; off < 16; off <<= 1) {
            float w1 = __shfl_xor(v1, off); int k1 = __shfl_xor(j1, off);
            float w2 = __shfl_xor(v2, off); int k2 = __shfl_xor(j2, off);
            if (better(w1, k1, v1, j1)) {
                if (better(v1, j1, w2, k2)) { v2 = v1; j2 = j1; }
                else                        { v2 = w2; j2 = k2; }
                v1 = w1; j1 = k1;
            } else if (better(w1, k1, v2, j2)) {
                v2 = w1; j2 = k1;
            }
        }

        float g0 = (iA == j1 || iA == j2) ? c0 : 0.f;
        float g1 = (iB == j1 || iB == j2) ? c1 : 0.f;
        float g2 = (iC == j1 || iC == j2) ? c2 : 0.f;
        float g3 = (iD == j1 || iD == j2) ? c3 : 0.f;

        // --- rank2 vs rank3 margin; flag uncertain tokens for fp64 repair ---
        float t0 = (iA == j1 || iA == j2) ? -3.0e38f : c0;
        float t1 = (iB == j1 || iB == j2) ? -3.0e38f : c1;
        float t2 = (iC == j1 || iC == j2) ? -3.0e38f : c2;
        float t3 = (iD == j1 || iD == j2) ? -3.0e38f : c3;
        float m3v = fmaxf(fmaxf(t0, t1), fmaxf(t2, t3));
        #pragma unroll
        for (int off = 8; off >= 1; off >>= 1)
            m3v = fmaxf(m3v, __shfl_xor(m3v, off));

        const int tl = wave * 16 + quad * 4 + rr;   // token within block
        bool flag = ((v2 - m3v) < 1e-4f) || (sx > 0.0f);
        if (flag && c16 == 0) {
            int pos = atomicAdd(flagCount, 1);
            if (pos < listCap) flagList[pos] = tokenBase + tl;
        }

        gtile[tl * 64 + iA] = g0;
        gtile[tl * 64 + iB] = g1;
        gtile[tl * 64 + iC] = g2;
        gtile[tl * 64 + iD] = g3;
    }

    __syncthreads();

    const uint4* src = reinterpret_cast<const uint4*>(gtile);
    uint4* dst = reinterpret_cast<uint4*>(out + (size_t)tokenBase * 64);
    dst[threadIdx.x]       = src[threadIdx.x];
    dst[threadIdx.x + 256] = src[threadIdx.x + 256];
    dst[threadIdx.x + 512] = src[threadIdx.x + 512];
    dst[threadIdx.x + 768] = src[threadIdx.x + 768];
}

// ---------------------------------------------------------------------------
// Legacy router (inline W split) — fallback when workspace is too small for
// the pre-split W area.  Identical to the originally verified kernel.
// ---------------------------------------------------------------------------
__global__ __launch_bounds__(256, 4)
void router_kernel_legacy(const float* __restrict__ tokens,
                          const int* __restrict__ tarr,
                          const float* __restrict__ Wg,
                          const float* __restrict__ bg,
                          float* __restrict__ out,
                          int* __restrict__ flagCount,
                          int* __restrict__ flagList,
                          int listCap)
{
    __shared__ __align__(16) float gtile[64 * 64];

    const int lane = threadIdx.x & 63;
    const int wave = threadIdx.x >> 6;
    const int c16  = lane & 15;
    const int quad = lane >> 4;

    const int tokenBase = blockIdx.x * 64;
    const int token     = tokenBase + wave * 16 + c16;

    const float4* ap = reinterpret_cast<const float4*>(tokens) + (size_t)token * 256 + quad * 2;
    const float4* wp0 = reinterpret_cast<const float4*>(Wg) + (size_t)(c16 +  0) * 256 + quad * 2;
    const float4* wp1 = reinterpret_cast<const float4*>(Wg) + (size_t)(c16 + 16) * 256 + quad * 2;
    const float4* wp2 = reinterpret_cast<const float4*>(Wg) + (size_t)(c16 + 32) * 256 + quad * 2;
    const float4* wp3 = reinterpret_cast<const float4*>(Wg) + (size_t)(c16 + 48) * 256 + quad * 2;

    floatx4 acc0 = {0.f, 0.f, 0.f, 0.f};
    floatx4 acc1 = acc0, acc2 = acc0, acc3 = acc0;

    for (int kb = 0; kb < 32; ++kb) {
        short8 ahi, alo;
        split8(ap[kb * 8], ap[kb * 8 + 1], ahi, alo);
        {
            short8 whi, wlo;
            split8(wp0[kb * 8], wp0[kb * 8 + 1], whi, wlo);
            acc0 = MFMA(ahi, whi, acc0);
            acc0 = MFMA(alo, whi, acc0);
            acc0 = MFMA(ahi, wlo, acc0);
        }
        {
            short8 whi, wlo;
            split8(wp1[kb * 8], wp1[kb * 8 + 1], whi, wlo);
            acc1 = MFMA(ahi, whi, acc1);
            acc1 = MFMA(alo, whi, acc1);
            acc1 = MFMA(ahi, wlo, acc1);
        }
        {
            short8 whi, wlo;
            split8(wp2[kb * 8], wp2[kb * 8 + 1], whi, wlo);
            acc2 = MFMA(ahi, whi, acc2);
            acc2 = MFMA(alo, whi, acc2);
            acc2 = MFMA(ahi, wlo, acc2);
        }
        {
            short8 whi, wlo;
            split8(wp3[kb * 8], wp3[kb * 8 + 1], whi, wlo);
            acc3 = MFMA(ahi, whi, acc3);
            acc3 = MFMA(alo, whi, acc3);
            acc3 = MFMA(ahi, wlo, acc3);
        }
    }

    const float b0f = bg[c16 +  0];
    const float b1f = bg[c16 + 16];
    const float b2f = bg[c16 + 32];
    const float b3f = bg[c16 + 48];

    const float tb  = (float)tarr[tokenBase >> 12];
    const float cap = 0.5f + 1.1f * (tb / 1000.0f);

    const float A1 = 0.85f;
    const float A2 = 0.15f / 64.0f;

    #pragma unroll
    for (int r = 0; r < 4; ++r) {
        float l0 = acc0[r] + b0f;
        float l1 = acc1[r] + b1f;
        float l2 = acc2[r] + b2f;
        float l3 = acc3[r] + b3f;

        float mx = fmaxf(fmaxf(l0, l1), fmaxf(l2, l3));
        #pragma unroll
        for (int off = 8; off >= 1; off >>= 1)
            mx = fmaxf(mx, __shfl_xor(mx, off));

        float e0 = expf(l0 - mx), e1 = expf(l1 - mx);
        float e2 = expf(l2 - mx), e3 = expf(l3 - mx);
        float s = e0 + e1 + e2 + e3;
        #pragma unroll
        for (int off = 8; off >= 1; off >>= 1)
            s += __shfl_xor(s, off);
        float inv = 1.0f / s;

        float p0 = A1 * (e0 * inv) + A2;
        float p1 = A1 * (e1 * inv) + A2;
        float p2 = A1 * (e2 * inv) + A2;
        float p3 = A1 * (e3 * inv) + A2;

        float x0 = fmaxf(p0 - cap, 0.f), x1 = fmaxf(p1 - cap, 0.f);
        float x2 = fmaxf(p2 - cap, 0.f), x3 = fmaxf(p3 - cap, 0.f);
        float m0 = p0 - x0, m1 = p1 - x1, m2 = p2 - x2, m3 = p3 - x3;
        float h0 = fmaxf(cap - m0, 0.f), h1 = fmaxf(cap - m1, 0.f);
        float h2 = fmaxf(cap - m2, 0.f), h3 = fmaxf(cap - m3, 0.f);
        float sx = x0 + x1 + x2 + x3;
        float sh = h0 + h1 + h2 + h3;
        #pragma unroll
        for (int off = 8; off >= 1; off >>= 1) {
            sx += __shfl_xor(sx, off);
            sh += __shfl_xor(sh, off);
        }
        sh = fmaxf(sh, 1e-8f);
        float sc = sx / sh;
        float c0 = m0 + sc * h0;
        float c1 = m1 + sc * h1;
        float c2 = m2 + sc * h2;
        float c3 = m3 + sc * h3;

        const int iA = c16, iB = c16 + 16, iC = c16 + 32, iD = c16 + 48;
        float v1, v2; int j1, j2;
        if (better(c0, iA, c1, iB)) { v1 = c0; j1 = iA; v2 = c1; j2 = iB; }
        else                        { v1 = c1; j1 = iB; v2 = c0; j2 = iA; }
        if (better(c2, iC, v1, j1))      { v2 = v1; j2 = j1; v1 = c2; j1 = iC; }
        else if (better(c2, iC, v2, j2)) { v2 = c2; j2 = iC; }
        if (better(c3, iD, v1, j1))      { v2 = v1; j2 = j1; v1 = c3; j1 = iD; }
        else if (better(c3, iD, v2, j2)) { v2 = c3; j2 = iD; }

        #pragma unroll
        for (int off = 1; off < 16; off <<= 1) {
            float w1 = __shfl_xor(v1, off); int k1 = __shfl_xor(j1, off);
            float w2 = __shfl_xor(v2, off); int k2 = __shfl_xor(j2, off);
            if (better(w1, k1, v1, j1)) {
                if (better(v1, j1, w2, k2)) { v2 = v1; j2 = j1; }
                else                        { v2 = w2; j2 = k2; }
                v1 = w1; j1 = k1;
            } else if (better(w1, k1, v2, j2)) {
                v2 = w1; j2 = k1;
            }
        }

        float g0 = (iA == j1 || iA == j2) ? c0 : 0.f;
        float g1 = (iB == j1 || iB == j2) ? c1 : 0.f;
        float g2 = (iC == j1 || iC == j2) ? c2 : 0.f;
        float g3 = (iD == j1 || iD == j2) ? c3 : 0.f;

        float t0 = (iA == j1 || iA == j2) ? -3.0e38f : c0;
        float t1 = (iB == j1 || iB == j2) ? -3.0e38f : c1;
        float t2 = (iC == j1 || iC == j2) ? -3.0e38f : c2;
        float t3 = (iD == j1 || iD == j2) ? -3.0e38f : c3;
        float m3v = fmaxf(fmaxf(t0, t1), fmaxf(t2, t3));
        #pragma unroll
        for (int off = 8; off >= 1; off >>= 1)
            m3v = fmaxf(m3v, __shfl_xor(m3v, off));

        const int tl = wave * 16 + quad * 4 + r;
        bool flag = ((v2 - m3v) < 1e-4f) || (sx > 0.0f);
        if (flag && c16 == 0) {
            int pos = atomicAdd(flagCount, 1);
            if (pos < listCap) flagList[pos] = tokenBase + tl;
        }

        gtile[tl * 64 + iA] = g0;
        gtile[tl * 64 + iB] = g1;
        gtile[tl * 64 + iC] = g2;
        gtile[tl * 64 + iD] = g3;
    }

    __syncthreads();

    const uint4* src = reinterpret_cast<const uint4*>(gtile);
    uint4* dst = reinterpret_cast<uint4*>(out + (size_t)tokenBase * 64);
    dst[threadIdx.x]       = src[threadIdx.x];
    dst[threadIdx.x + 256] = src[threadIdx.x + 256];
    dst[threadIdx.x + 512] = src[threadIdx.x + 512];
    dst[threadIdx.x + 768] = src[threadIdx.x + 768];
}

// ---------------------------------------------------------------------------
// fp64 exact recompute of flagged tokens — batched: 8 tokens share one W pass.
// ---------------------------------------------------------------------------
__global__ __launch_bounds__(256)
void repair_kernel(const float* __restrict__ tokens,
                   const int* __restrict__ tarr,
                   const float* __restrict__ Wg,
                   const float* __restrict__ bg,
                   float* __restrict__ out,
                   const int* __restrict__ cnt,
                   const int* __restrict__ list,
                   int listCap)
{
    __shared__ __align__(16) float atile[8][1024];   // 32 KB
    __shared__ double red[256];                      //  2 KB
    int count = cnt[0];
    if (count > listCap) count = listCap;

    const int e    = threadIdx.x & 63;   // expert
    const int part = threadIdx.x >> 6;   // k-quarter

    for (int base = blockIdx.x * 8; base < count; base += gridDim.x * 8) {
        const int n = min(8, count - base);

        #pragma unroll
        for (int t = 0; t < 8; ++t) {
            if (t < n) {
                const float4* src =
                    reinterpret_cast<const float4*>(tokens + (size_t)list[base + t] * 1024);
                reinterpret_cast<float4*>(atile[t])[threadIdx.x] = src[threadIdx.x];
            }
        }
        __syncthreads();

        double acc0 = 0.0, acc1 = 0.0, acc2 = 0.0, acc3 = 0.0;
        double acc4 = 0.0, acc5 = 0.0, acc6 = 0.0, acc7 = 0.0;
        const float* wrow = Wg + (size_t)e * 1024 + part * 256;
        const int ko = part * 256;
        for (int k = 0; k < 256; k += 4) {
            float4 wv = *reinterpret_cast<const float4*>(wrow + k);
            const double w0 = (double)wv.x, w1 = (double)wv.y;
            const double w2 = (double)wv.z, w3 = (double)wv.w;
            #define ACC(T, A)                                                   \
                A = fma((double)atile[T][ko + k    ], w0, A);                    \
                A = fma((double)atile[T][ko + k + 1], w1, A);                    \
                A = fma((double)atile[T][ko + k + 2], w2, A);                    \
                A = fma((double)atile[T][ko + k + 3], w3, A);
            ACC(0, acc0) ACC(1, acc1) ACC(2, acc2) ACC(3, acc3)
            ACC(4, acc4) ACC(5, acc5) ACC(6, acc6) ACC(7, acc7)
            #undef ACC
        }

        #pragma unroll
        for (int t = 0; t < 8; ++t) {
            if (t >= n) break;
            double accT = (t == 0) ? acc0 : (t == 1) ? acc1 : (t == 2) ? acc2 :
                          (t == 3) ? acc3 : (t == 4) ? acc4 : (t == 5) ? acc5 :
                          (t == 6) ? acc6 : acc7;
            red[threadIdx.x] = accT;
            __syncthreads();

            if (threadIdx.x < 64) {
                const int token = list[base + t];
                double l = ((red[e] + red[64 + e]) + (red[128 + e] + red[192 + e]))
                         + (double)bg[e];

                double mxv = l;
                #pragma unroll
                for (int off = 32; off >= 1; off >>= 1)
                    mxv = fmax(mxv, __shfl_xor(mxv, off));
                double ex = exp(l - mxv);
                double s = ex;
                #pragma unroll
                for (int off = 32; off >= 1; off >>= 1)
                    s += __shfl_xor(s, off);

                const double alpha = 0.15;
                double p = (1.0 - alpha) * (ex / s) + alpha / 64.0;

                double tb  = (double)tarr[token >> 12];
                double capv = 0.5 + (0.6 + 0.5) * (tb / 1000.0);
                double x = fmax(p - capv, 0.0);
                double m = p - x;
                double h = fmax(capv - m, 0.0);
                double sx = x, sh = h;
                #pragma unroll
                for (int off = 32; off >= 1; off >>= 1) {
                    sx += __shfl_xor(sx, off);
                    sh += __shfl_xor(sh, off);
                }
                sh = fmax(sh, 1e-8);
                double c = m + (sx / sh) * h;

                double v1 = c, v2 = -1.0e300;
                int j1 = e, j2 = 127;
                #pragma unroll
                for (int off = 1; off < 64; off <<= 1) {
                    double w1 = __shfl_xor(v1, off); int k1 = __shfl_xor(j1, off);
                    double w2 = __shfl_xor(v2, off); int k2 = __shfl_xor(j2, off);
                    if (betterd(w1, k1, v1, j1)) {
                        if (betterd(v1, j1, w2, k2)) { v2 = v1; j2 = j1; }
                        else                         { v2 = w2; j2 = k2; }
                        v1 = w1; j1 = k1;
                    } else if (betterd(w1, k1, v2, j2)) {
                        v2 = w1; j2 = k1;
                    }
                }

                float g = (e == j1 || e == j2) ? (float)c : 0.0f;
                out[(size_t)token * 64 + e] = g;
            }
            __syncthreads();
        }
    }
}

extern "C" void kernel_launch(void* const* d_in, const int* in_sizes, int n_in,
                              void* d_out, int out_size, void* d_ws, size_t ws_size,
                              hipStream_t stream) {
    const float* tokens = (const float*)d_in[0];
    const int*   t      = (const int*)d_in[1];
    const float* Wg     = (const float*)d_in[2];
    const float* bg     = (const float*)d_in[3];
    float*       outp   = (float*)d_out;

    int* wsI = (int*)d_ws;
    const long long wsInts = (long long)(ws_size / 4);

    // layout: [0..15] counter | [16 ..) whi 128KB | wlo 128KB | flagList
    const int  WHALF   = 32768;                  // ints per bf16 half (64*1024 shorts)
    const long long listOff = 16 + 2LL * WHALF;  // = 65552 ints
    long long cap = wsInts - listOff;
    if (cap > 65536) cap = 65536;

    hipMemsetAsync(d_ws, 0, 64, stream);   // zero flag counter (capturable)

    if (cap >= 32768) {
        short* whi  = (short*)(wsI + 16);
        short* wlo  = (short*)(wsI + 16 + WHALF);
        int*   list = wsI + listOff;
        wsplit_kernel<<<dim3(32), dim3(256), 0, stream>>>(Wg, whi, wlo);
        router_kernel<<<dim3(65536 / 64), dim3(256), 0, stream>>>(
            tokens, t, bg, outp, wsI, list, (int)cap, whi, wlo);
        repair_kernel<<<dim3(256), dim3(256), 0, stream>>>(
            tokens, t, Wg, bg, outp, wsI, list, (int)cap);
    } else {
        long long cap2 = wsInts - 16;
        if (cap2 < 0) cap2 = 0;
        if (cap2 > 65536) cap2 = 65536;
        router_kernel_legacy<<<dim3(65536 / 64), dim3(256), 0, stream>>>(
            tokens, t, Wg, bg, outp, wsI, wsI + 16, (int)cap2);
        repair_kernel<<<dim3(256), dim3(256), 0, stream>>>(
            tokens, t, Wg, bg, outp, wsI, wsI + 16, (int)cap2);
    }
}

// Round 4
// 448.172 us; speedup vs baseline: 1.0005x; 1.0005x over previous
//
#include <hip/hip_runtime.h>
#include <hip/hip_bf16.h>

typedef __attribute__((ext_vector_type(8))) short short8;   // 8 x bf16 = 4 VGPRs
typedef __attribute__((ext_vector_type(4))) short sh4;      // 4 x bf16 = 8 bytes
typedef __attribute__((ext_vector_type(4))) float floatx4;  // MFMA C/D

// total ordering: larger value wins; tie -> smaller index wins (jax.lax.top_k)
__device__ __forceinline__ bool better(float va, int ia, float vb, int ib) {
    return (va > vb) || (va == vb && ia < ib);
}
__device__ __forceinline__ bool betterd(double va, int ia, double vb, int ib) {
    return (va > vb) || (va == vb && ia < ib);
}

__device__ __forceinline__ short bf16_rn(float f) {
    __hip_bfloat16 h = __float2bfloat16(f);   // round-to-nearest-even
    return *reinterpret_cast<short*>(&h);
}
__device__ __forceinline__ float bf16_up(short s) {
    return __uint_as_float(((unsigned)(unsigned short)s) << 16);
}

// split 8 fp32 into bf16 hi + bf16 lo fragments (a ~= hi + lo)
__device__ __forceinline__ void split8(float4 a, float4 b, short8& hi, short8& lo) {
    float v[8] = {a.x, a.y, a.z, a.w, b.x, b.y, b.z, b.w};
    #pragma unroll
    for (int i = 0; i < 8; ++i) {
        short h = bf16_rn(v[i]);
        hi[i] = h;
        lo[i] = bf16_rn(v[i] - bf16_up(h));
    }
}

#define MFMA(A, B, C) __builtin_amdgcn_mfma_f32_16x16x32_bf16((A), (B), (C), 0, 0, 0)

// async global -> LDS, 16B per lane.  LDS dest = wave-uniform base + lane*16.
__device__ __forceinline__ void gload16(const void* g, void* l) {
    __builtin_amdgcn_global_load_lds(
        (const __attribute__((address_space(1))) void*)g,
        (__attribute__((address_space(3))) void*)l,
        16, 0, 0);
}

// ---------------------------------------------------------------------------
// Prep: split W (64x1024 fp32) into bf16 hi/lo, PERMUTED so router staging and
// reads are both linear-in-lane.  Granule = 8 bf16 (16B).  Layout:
//   whi[c][g][q][e] : chunk c (32 k-floats), expert group g (experts 16g+e),
//                     k-octet q (k = 32c + 8q .. +7), e in 0..15.
//   idx = c*256 + g*64 + q*16 + e   (8192 granules, 128 KB per half)
// ---------------------------------------------------------------------------
__global__ __launch_bounds__(256)
void wsplit_kernel(const float* __restrict__ Wg,
                   short* __restrict__ whi,
                   short* __restrict__ wlo)
{
    const int idx = blockIdx.x * 256 + threadIdx.x;   // 32 blocks -> 8192 granules
    const int c = idx >> 8;
    const int g = (idx >> 6) & 3;
    const int q = (idx >> 4) & 3;
    const int e = idx & 15;
    const float* src = Wg + (size_t)(g * 16 + e) * 1024 + c * 32 + q * 8;
    float4 v0 = reinterpret_cast<const float4*>(src)[0];
    float4 v1 = reinterpret_cast<const float4*>(src)[1];
    short8 hi, lo;
    split8(v0, v1, hi, lo);
    reinterpret_cast<short8*>(whi)[idx] = hi;
    reinterpret_cast<short8*>(wlo)[idx] = lo;
}

// ---------------------------------------------------------------------------
// Main router, hybrid transport:
//   A (wave-private): direct global->VGPR fragment loads, 2-chunk register
//     ping-pong (named regs A/B, compile-time indexed).  No LDS round trip.
//   W (block-shared): pre-split bf16 hi/lo staged via global_load_lds into a
//     2 x 8KB LDS double buffer, conflict-free linear layout (all ds_reads are
//     uniform base + lane*16).  2 DMA per wave per chunk.
//   Counted vmcnt(4): one full chunk (2 W-DMA + 2 A-loads) stays in flight
//   across each barrier; drain to 0 only at the last peeled chunk.  Issue
//   positions pinned by asm memory clobbers so the count is exact.
//   LDS = 16KB wbuf + 16KB gtile = 32KB -> 4 blocks/CU (grid-limited).
// Numerics bitwise identical to all prior rounds: same fragment values,
// same split8, same MFMA order.
// ---------------------------------------------------------------------------
__global__ __launch_bounds__(256, 2)
void router_kernel(const float* __restrict__ tokens,
                   const int* __restrict__ tarr,
                   const float* __restrict__ bg,
                   float* __restrict__ out,
                   int* __restrict__ flagCount,
                   int* __restrict__ flagList,
                   int listCap,
                   const short* __restrict__ whi,
                   const short* __restrict__ wlo)
{
    __shared__ __align__(16) float gtile[64 * 64];   // 16 KB gate tile
    __shared__ __align__(16) char  wbuf[2][8192];    // 16 KB W dbuf (Whi | Wlo)

    const int lane = threadIdx.x & 63;
    const int wave = threadIdx.x >> 6;
    const int c16  = lane & 15;   // token-within-wave (A row) / expert-within-group
    const int quad = lane >> 4;   // k-octet selector

    const int tokenBase = blockIdx.x * 64;
    const int token     = tokenBase + wave * 16 + c16;

    // A fragment source: floats [token*1024 + c*32 + quad*8 .. +7]
    const float4* ap = reinterpret_cast<const float4*>(tokens) + (size_t)token * 256 + quad * 2;

    // W staging source (contiguous 1KB per wave per half per chunk)
    const char* hS = (const char*)whi + wave * 1024 + (size_t)lane * 16;
    const char* lS = (const char*)wlo + wave * 1024 + (size_t)lane * 16;
    char* wb0h = wbuf[0];
    char* wb1h = wbuf[1];

    const int wRd = lane * 16;   // lane's W read offset (q=quad, e=c16 granule)

    floatx4 acc0 = {0.f, 0.f, 0.f, 0.f};
    floatx4 acc1 = acc0, acc2 = acc0, acc3 = acc0;

#define STAGE_W(c, wb)  do {                                              \
        gload16(hS + (size_t)(c) * 4096, (wb) + wave * 1024);             \
        gload16(lS + (size_t)(c) * 4096, (wb) + 4096 + wave * 1024);      \
    } while (0)

#define LOAD_A(c, A0, A1)  do {                                           \
        (A0) = ap[(c) * 8];                                               \
        (A1) = ap[(c) * 8 + 1];                                           \
    } while (0)

#define COMPUTE(wb, A0, A1)  do {                                         \
        const char* bW = (wb);                                            \
        short8 h0 = *(const short8*)(bW +    0 + wRd);                    \
        short8 h1 = *(const short8*)(bW + 1024 + wRd);                    \
        short8 h2 = *(const short8*)(bW + 2048 + wRd);                    \
        short8 h3 = *(const short8*)(bW + 3072 + wRd);                    \
        short8 l0 = *(const short8*)(bW + 4096 + wRd);                    \
        short8 l1 = *(const short8*)(bW + 5120 + wRd);                    \
        short8 l2 = *(const short8*)(bW + 6144 + wRd);                    \
        short8 l3 = *(const short8*)(bW + 7168 + wRd);                    \
        short8 ahi, alo;                                                  \
        split8((A0), (A1), ahi, alo);                                     \
        acc0 = MFMA(ahi, h0, acc0); acc0 = MFMA(alo, h0, acc0); acc0 = MFMA(ahi, l0, acc0); \
        acc1 = MFMA(ahi, h1, acc1); acc1 = MFMA(alo, h1, acc1); acc1 = MFMA(ahi, l1, acc1); \
        acc2 = MFMA(ahi, h2, acc2); acc2 = MFMA(alo, h2, acc2); acc2 = MFMA(ahi, l2, acc2); \
        acc3 = MFMA(ahi, h3, acc3); acc3 = MFMA(alo, h3, acc3); acc3 = MFMA(ahi, l3, acc3); \
    } while (0)

#define WAIT4  asm volatile("s_waitcnt vmcnt(4)" ::: "memory")
#define WAIT0  asm volatile("s_waitcnt vmcnt(0)" ::: "memory")
#define BAR    do { __builtin_amdgcn_s_barrier(); asm volatile("" ::: "memory"); } while (0)

    float4 a0A, a1A, a0B, a1B;

    // prologue: chunks 0 (buf0/regsA) and 1 (buf1/regsB) in flight
    STAGE_W(0, wb0h);  LOAD_A(0, a0A, a1A);
    STAGE_W(1, wb1h);  LOAD_A(1, a0B, a1B);

    #pragma unroll 1
    for (int cc = 0; cc < 15; ++cc) {
        const int c0 = 2 * cc;
        // ---- chunk c0 (even): buf0, regsA --------------------------------
        WAIT4;                         // chunk c0 landed; c0+1 stays in flight
        BAR;
        COMPUTE(wb0h, a0A, a1A);
        BAR;                           // all waves done reading buf0
        STAGE_W(c0 + 2, wb0h);  LOAD_A(c0 + 2, a0A, a1A);
        // ---- chunk c0+1 (odd): buf1, regsB -------------------------------
        WAIT4;
        BAR;
        COMPUTE(wb1h, a0B, a1B);
        BAR;
        STAGE_W(c0 + 3, wb1h);  LOAD_A(c0 + 3, a0B, a1B);
    }
    // ---- peeled tail: chunks 30, 31 (no further staging) ------------------
    WAIT4;                             // 30 landed; 31 in flight
    BAR;
    COMPUTE(wb0h, a0A, a1A);
    BAR;
    WAIT0;                             // final drain
    BAR;
    COMPUTE(wb1h, a0B, a1B);

#undef STAGE_W
#undef LOAD_A
#undef COMPUTE
#undef WAIT4
#undef WAIT0
#undef BAR

    const float b0f = bg[c16 +  0];
    const float b1f = bg[c16 + 16];
    const float b2f = bg[c16 + 32];
    const float b3f = bg[c16 + 48];

    const float tb  = (float)tarr[tokenBase >> 12];   // 4096 tokens per batch
    const float cap = 0.5f + 1.1f * (tb / 1000.0f);

    const float A1 = 0.85f;            // 1 - alpha, alpha = 0.15
    const float A2 = 0.15f / 64.0f;    // alpha / E

    #pragma unroll
    for (int rr = 0; rr < 4; ++rr) {
        float l0 = acc0[rr] + b0f;
        float l1 = acc1[rr] + b1f;
        float l2 = acc2[rr] + b2f;
        float l3 = acc3[rr] + b3f;

        // --- softmax over 64 experts (16-lane group x 4 local) ---
        float mx = fmaxf(fmaxf(l0, l1), fmaxf(l2, l3));
        #pragma unroll
        for (int off = 8; off >= 1; off >>= 1)
            mx = fmaxf(mx, __shfl_xor(mx, off));

        float e0 = expf(l0 - mx), e1 = expf(l1 - mx);
        float e2 = expf(l2 - mx), e3 = expf(l3 - mx);
        float s = e0 + e1 + e2 + e3;
        #pragma unroll
        for (int off = 8; off >= 1; off >>= 1)
            s += __shfl_xor(s, off);
        float inv = 1.0f / s;

        // --- routing floor ---
        float p0 = A1 * (e0 * inv) + A2;
        float p1 = A1 * (e1 * inv) + A2;
        float p2 = A1 * (e2 * inv) + A2;
        float p3 = A1 * (e3 * inv) + A2;

        // --- hard cap with excess redistribution ---
        float x0 = fmaxf(p0 - cap, 0.f), x1 = fmaxf(p1 - cap, 0.f);
        float x2 = fmaxf(p2 - cap, 0.f), x3 = fmaxf(p3 - cap, 0.f);
        float m0 = p0 - x0, m1 = p1 - x1, m2 = p2 - x2, m3 = p3 - x3;
        float h0 = fmaxf(cap - m0, 0.f), h1 = fmaxf(cap - m1, 0.f);
        float h2 = fmaxf(cap - m2, 0.f), h3 = fmaxf(cap - m3, 0.f);
        float sx = x0 + x1 + x2 + x3;
        float sh = h0 + h1 + h2 + h3;
        #pragma unroll
        for (int off = 8; off >= 1; off >>= 1) {
            sx += __shfl_xor(sx, off);
            sh += __shfl_xor(sh, off);
        }
        sh = fmaxf(sh, 1e-8f);
        float sc = sx / sh;
        float c0 = m0 + sc * h0;
        float c1 = m1 + sc * h1;
        float c2 = m2 + sc * h2;
        float c3 = m3 + sc * h3;

        // --- top-2 (value desc, tie -> smaller expert index) ---
        const int iA = c16, iB = c16 + 16, iC = c16 + 32, iD = c16 + 48;
        float v1, v2; int j1, j2;
        if (better(c0, iA, c1, iB)) { v1 = c0; j1 = iA; v2 = c1; j2 = iB; }
        else                        { v1 = c1; j1 = iB; v2 = c0; j2 = iA; }
        if (better(c2, iC, v1, j1))      { v2 = v1; j2 = j1; v1 = c2; j1 = iC; }
        else if (better(c2, iC, v2, j2)) { v2 = c2; j2 = iC; }
        if (better(c3, iD, v1, j1))      { v2 = v1; j2 = j1; v1 = c3; j1 = iD; }
        else if (better(c3, iD, v2, j2)) { v2 = c3; j2 = iD; }

        #pragma unroll
        for (int off = 1; off < 16; off <<= 1) {
            float w1 = __shfl_xor(v1, off); int k1 = __shfl_xor(j1, off);
            float w2 = __shfl_xor(v2, off); int k2 = __shfl_xor(j2, off);
            if (better(w1, k1, v1, j1)) {
                if (better(v1, j1, w2, k2)) { v2 = v1; j2 = j1; }
                else                        { v2 = w2; j2 = k2; }
                v1 = w1; j1 = k1;
            } else if (better(w1, k1, v2, j2)) {
                v2 = w1; j2 = k1;
            }
        }

        float g0 = (iA == j1 || iA == j2) ? c0 : 0.f;
        float g1 = (iB == j1 || iB == j2) ? c1 : 0.f;
        float g2 = (iC == j1 || iC == j2) ? c2 : 0.f;
        float g3 = (iD == j1 || iD == j2) ? c3 : 0.f;

        // --- rank2 vs rank3 margin; flag uncertain tokens for fp64 repair ---
        float t0 = (iA == j1 || iA == j2) ? -3.0e38f : c0;
        float t1 = (iB == j1 || iB == j2) ? -3.0e38f : c1;
        float t2 = (iC == j1 || iC == j2) ? -3.0e38f : c2;
        float t3 = (iD == j1 || iD == j2) ? -3.0e38f : c3;
        float m3v = fmaxf(fmaxf(t0, t1), fmaxf(t2, t3));
        #pragma unroll
        for (int off = 8; off >= 1; off >>= 1)
            m3v = fmaxf(m3v, __shfl_xor(m3v, off));

        const int tl = wave * 16 + quad * 4 + rr;   // token within block
        bool flag = ((v2 - m3v) < 1e-4f) || (sx > 0.0f);
        if (flag && c16 == 0) {
            int pos = atomicAdd(flagCount, 1);
            if (pos < listCap) flagList[pos] = tokenBase + tl;
        }

        gtile[tl * 64 + iA] = g0;
        gtile[tl * 64 + iB] = g1;
        gtile[tl * 64 + iC] = g2;
        gtile[tl * 64 + iD] = g3;
    }

    __syncthreads();

    const uint4* src = reinterpret_cast<const uint4*>(gtile);
    uint4* dst = reinterpret_cast<uint4*>(out + (size_t)tokenBase * 64);
    dst[threadIdx.x]       = src[threadIdx.x];
    dst[threadIdx.x + 256] = src[threadIdx.x + 256];
    dst[threadIdx.x + 512] = src[threadIdx.x + 512];
    dst[threadIdx.x + 768] = src[threadIdx.x + 768];
}

// ---------------------------------------------------------------------------
// Legacy router (inline W split) — fallback when workspace is too small for
// the pre-split W area.  Identical to the originally verified kernel.
// ---------------------------------------------------------------------------
__global__ __launch_bounds__(256, 4)
void router_kernel_legacy(const float* __restrict__ tokens,
                          const int* __restrict__ tarr,
                          const float* __restrict__ Wg,
                          const float* __restrict__ bg,
                          float* __restrict__ out,
                          int* __restrict__ flagCount,
                          int* __restrict__ flagList,
                          int listCap)
{
    __shared__ __align__(16) float gtile[64 * 64];

    const int lane = threadIdx.x & 63;
    const int wave = threadIdx.x >> 6;
    const int c16  = lane & 15;
    const int quad = lane >> 4;

    const int tokenBase = blockIdx.x * 64;
    const int token     = tokenBase + wave * 16 + c16;

    const float4* ap = reinterpret_cast<const float4*>(tokens) + (size_t)token * 256 + quad * 2;
    const float4* wp0 = reinterpret_cast<const float4*>(Wg) + (size_t)(c16 +  0) * 256 + quad * 2;
    const float4* wp1 = reinterpret_cast<const float4*>(Wg) + (size_t)(c16 + 16) * 256 + quad * 2;
    const float4* wp2 = reinterpret_cast<const float4*>(Wg) + (size_t)(c16 + 32) * 256 + quad * 2;
    const float4* wp3 = reinterpret_cast<const float4*>(Wg) + (size_t)(c16 + 48) * 256 + quad * 2;

    floatx4 acc0 = {0.f, 0.f, 0.f, 0.f};
    floatx4 acc1 = acc0, acc2 = acc0, acc3 = acc0;

    for (int kb = 0; kb < 32; ++kb) {
        short8 ahi, alo;
        split8(ap[kb * 8], ap[kb * 8 + 1], ahi, alo);
        {
            short8 whi, wlo;
            split8(wp0[kb * 8], wp0[kb * 8 + 1], whi, wlo);
            acc0 = MFMA(ahi, whi, acc0);
            acc0 = MFMA(alo, whi, acc0);
            acc0 = MFMA(ahi, wlo, acc0);
        }
        {
            short8 whi, wlo;
            split8(wp1[kb * 8], wp1[kb * 8 + 1], whi, wlo);
            acc1 = MFMA(ahi, whi, acc1);
            acc1 = MFMA(alo, whi, acc1);
            acc1 = MFMA(ahi, wlo, acc1);
        }
        {
            short8 whi, wlo;
            split8(wp2[kb * 8], wp2[kb * 8 + 1], whi, wlo);
            acc2 = MFMA(ahi, whi, acc2);
            acc2 = MFMA(alo, whi, acc2);
            acc2 = MFMA(ahi, wlo, acc2);
        }
        {
            short8 whi, wlo;
            split8(wp3[kb * 8], wp3[kb * 8 + 1], whi, wlo);
            acc3 = MFMA(ahi, whi, acc3);
            acc3 = MFMA(alo, whi, acc3);
            acc3 = MFMA(ahi, wlo, acc3);
        }
    }

    const float b0f = bg[c16 +  0];
    const float b1f = bg[c16 + 16];
    const float b2f = bg[c16 + 32];
    const float b3f = bg[c16 + 48];

    const float tb  = (float)tarr[tokenBase >> 12];
    const float cap = 0.5f + 1.1f * (tb / 1000.0f);

    const float A1 = 0.85f;
    const float A2 = 0.15f / 64.0f;

    #pragma unroll
    for (int r = 0; r < 4; ++r) {
        float l0 = acc0[r] + b0f;
        float l1 = acc1[r] + b1f;
        float l2 = acc2[r] + b2f;
        float l3 = acc3[r] + b3f;

        float mx = fmaxf(fmaxf(l0, l1), fmaxf(l2, l3));
        #pragma unroll
        for (int off = 8; off >= 1; off >>= 1)
            mx = fmaxf(mx, __shfl_xor(mx, off));

        float e0 = expf(l0 - mx), e1 = expf(l1 - mx);
        float e2 = expf(l2 - mx), e3 = expf(l3 - mx);
        float s = e0 + e1 + e2 + e3;
        #pragma unroll
        for (int off = 8; off >= 1; off >>= 1)
            s += __shfl_xor(s, off);
        float inv = 1.0f / s;

        float p0 = A1 * (e0 * inv) + A2;
        float p1 = A1 * (e1 * inv) + A2;
        float p2 = A1 * (e2 * inv) + A2;
        float p3 = A1 * (e3 * inv) + A2;

        float x0 = fmaxf(p0 - cap, 0.f), x1 = fmaxf(p1 - cap, 0.f);
        float x2 = fmaxf(p2 - cap, 0.f), x3 = fmaxf(p3 - cap, 0.f);
        float m0 = p0 - x0, m1 = p1 - x1, m2 = p2 - x2, m3 = p3 - x3;
        float h0 = fmaxf(cap - m0, 0.f), h1 = fmaxf(cap - m1, 0.f);
        float h2 = fmaxf(cap - m2, 0.f), h3 = fmaxf(cap - m3, 0.f);
        float sx = x0 + x1 + x2 + x3;
        float sh = h0 + h1 + h2 + h3;
        #pragma unroll
        for (int off = 8; off >= 1; off >>= 1) {
            sx += __shfl_xor(sx, off);
            sh += __shfl_xor(sh, off);
        }
        sh = fmaxf(sh, 1e-8f);
        float sc = sx / sh;
        float c0 = m0 + sc * h0;
        float c1 = m1 + sc * h1;
        float c2 = m2 + sc * h2;
        float c3 = m3 + sc * h3;

        const int iA = c16, iB = c16 + 16, iC = c16 + 32, iD = c16 + 48;
        float v1, v2; int j1, j2;
        if (better(c0, iA, c1, iB)) { v1 = c0; j1 = iA; v2 = c1; j2 = iB; }
        else                        { v1 = c1; j1 = iB; v2 = c0; j2 = iA; }
        if (better(c2, iC, v1, j1))      { v2 = v1; j2 = j1; v1 = c2; j1 = iC; }
        else if (better(c2, iC, v2, j2)) { v2 = c2; j2 = iC; }
        if (better(c3, iD, v1, j1))      { v2 = v1; j2 = j1; v1 = c3; j1 = iD; }
        else if (better(c3, iD, v2, j2)) { v2 = c3; j2 = iD; }

        #pragma unroll
        for (int off = 1; off < 16; off <<= 1) {
            float w1 = __shfl_xor(v1, off); int k1 = __shfl_xor(j1, off);
            float w2 = __shfl_xor(v2, off); int k2 = __shfl_xor(j2, off);
            if (better(w1, k1, v1, j1)) {
                if (better(v1, j1, w2, k2)) { v2 = v1; j2 = j1; }
                else                        { v2 = w2; j2 = k2; }
                v1 = w1; j1 = k1;
            } else if (better(w1, k1, v2, j2)) {
                v2 = w1; j2 = k1;
            }
        }

        float g0 = (iA == j1 || iA == j2) ? c0 : 0.f;
        float g1 = (iB == j1 || iB == j2) ? c1 : 0.f;
        float g2 = (iC == j1 || iC == j2) ? c2 : 0.f;
        float g3 = (iD == j1 || iD == j2) ? c3 : 0.f;

        float t0 = (iA == j1 || iA == j2) ? -3.0e38f : c0;
        float t1 = (iB == j1 || iB == j2) ? -3.0e38f : c1;
        float t2 = (iC == j1 || iC == j2) ? -3.0e38f : c2;
        float t3 = (iD == j1 || iD == j2) ? -3.0e38f : c3;
        float m3v = fmaxf(fmaxf(t0, t1), fmaxf(t2, t3));
        #pragma unroll
        for (int off = 8; off >= 1; off >>= 1)
            m3v = fmaxf(m3v, __shfl_xor(m3v, off));

        const int tl = wave * 16 + quad * 4 + r;
        bool flag = ((v2 - m3v) < 1e-4f) || (sx > 0.0f);
        if (flag && c16 == 0) {
            int pos = atomicAdd(flagCount, 1);
            if (pos < listCap) flagList[pos] = tokenBase + tl;
        }

        gtile[tl * 64 + iA] = g0;
        gtile[tl * 64 + iB] = g1;
        gtile[tl * 64 + iC] = g2;
        gtile[tl * 64 + iD] = g3;
    }

    __syncthreads();

    const uint4* src = reinterpret_cast<const uint4*>(gtile);
    uint4* dst = reinterpret_cast<uint4*>(out + (size_t)tokenBase * 64);
    dst[threadIdx.x]       = src[threadIdx.x];
    dst[threadIdx.x + 256] = src[threadIdx.x + 256];
    dst[threadIdx.x + 512] = src[threadIdx.x + 512];
    dst[threadIdx.x + 768] = src[threadIdx.x + 768];
}

// ---------------------------------------------------------------------------
// fp64 exact recompute of flagged tokens — batched: 8 tokens share one W pass.
// ---------------------------------------------------------------------------
__global__ __launch_bounds__(256)
void repair_kernel(const float* __restrict__ tokens,
                   const int* __restrict__ tarr,
                   const float* __restrict__ Wg,
                   const float* __restrict__ bg,
                   float* __restrict__ out,
                   const int* __restrict__ cnt,
                   const int* __restrict__ list,
                   int listCap)
{
    __shared__ __align__(16) float atile[8][1024];   // 32 KB
    __shared__ double red[256];                      //  2 KB
    int count = cnt[0];
    if (count > listCap) count = listCap;

    const int e    = threadIdx.x & 63;   // expert
    const int part = threadIdx.x >> 6;   // k-quarter

    for (int base = blockIdx.x * 8; base < count; base += gridDim.x * 8) {
        const int n = min(8, count - base);

        #pragma unroll
        for (int t = 0; t < 8; ++t) {
            if (t < n) {
                const float4* src =
                    reinterpret_cast<const float4*>(tokens + (size_t)list[base + t] * 1024);
                reinterpret_cast<float4*>(atile[t])[threadIdx.x] = src[threadIdx.x];
            }
        }
        __syncthreads();

        double acc0 = 0.0, acc1 = 0.0, acc2 = 0.0, acc3 = 0.0;
        double acc4 = 0.0, acc5 = 0.0, acc6 = 0.0, acc7 = 0.0;
        const float* wrow = Wg + (size_t)e * 1024 + part * 256;
        const int ko = part * 256;
        for (int k = 0; k < 256; k += 4) {
            float4 wv = *reinterpret_cast<const float4*>(wrow + k);
            const double w0 = (double)wv.x, w1 = (double)wv.y;
            const double w2 = (double)wv.z, w3 = (double)wv.w;
            #define ACC(T, A)                                                   \
                A = fma((double)atile[T][ko + k    ], w0, A);                    \
                A = fma((double)atile[T][ko + k + 1], w1, A);                    \
                A = fma((double)atile[T][ko + k + 2], w2, A);                    \
                A = fma((double)atile[T][ko + k + 3], w3, A);
            ACC(0, acc0) ACC(1, acc1) ACC(2, acc2) ACC(3, acc3)
            ACC(4, acc4) ACC(5, acc5) ACC(6, acc6) ACC(7, acc7)
            #undef ACC
        }

        #pragma unroll
        for (int t = 0; t < 8; ++t) {
            if (t >= n) break;
            double accT = (t == 0) ? acc0 : (t == 1) ? acc1 : (t == 2) ? acc2 :
                          (t == 3) ? acc3 : (t == 4) ? acc4 : (t == 5) ? acc5 :
                          (t == 6) ? acc6 : acc7;
            red[threadIdx.x] = accT;
            __syncthreads();

            if (threadIdx.x < 64) {
                const int token = list[base + t];
                double l = ((red[e] + red[64 + e]) + (red[128 + e] + red[192 + e]))
                         + (double)bg[e];

                double mxv = l;
                #pragma unroll
                for (int off = 32; off >= 1; off >>= 1)
                    mxv = fmax(mxv, __shfl_xor(mxv, off));
                double ex = exp(l - mxv);
                double s = ex;
                #pragma unroll
                for (int off = 32; off >= 1; off >>= 1)
                    s += __shfl_xor(s, off);

                const double alpha = 0.15;
                double p = (1.0 - alpha) * (ex / s) + alpha / 64.0;

                double tb  = (double)tarr[token >> 12];
                double capv = 0.5 + (0.6 + 0.5) * (tb / 1000.0);
                double x = fmax(p - capv, 0.0);
                double m = p - x;
                double h = fmax(capv - m, 0.0);
                double sx = x, sh = h;
                #pragma unroll
                for (int off = 32; off >= 1; off >>= 1) {
                    sx += __shfl_xor(sx, off);
                    sh += __shfl_xor(sh, off);
                }
                sh = fmax(sh, 1e-8);
                double c = m + (sx / sh) * h;

                double v1 = c, v2 = -1.0e300;
                int j1 = e, j2 = 127;
                #pragma unroll
                for (int off = 1; off < 64; off <<= 1) {
                    double w1 = __shfl_xor(v1, off); int k1 = __shfl_xor(j1, off);
                    double w2 = __shfl_xor(v2, off); int k2 = __shfl_xor(j2, off);
                    if (betterd(w1, k1, v1, j1)) {
                        if (betterd(v1, j1, w2, k2)) { v2 = v1; j2 = j1; }
                        else                         { v2 = w2; j2 = k2; }
                        v1 = w1; j1 = k1;
                    } else if (betterd(w1, k1, v2, j2)) {
                        v2 = w1; j2 = k1;
                    }
                }

                float g = (e == j1 || e == j2) ? (float)c : 0.0f;
                out[(size_t)token * 64 + e] = g;
            }
            __syncthreads();
        }
    }
}

extern "C" void kernel_launch(void* const* d_in, const int* in_sizes, int n_in,
                              void* d_out, int out_size, void* d_ws, size_t ws_size,
                              hipStream_t stream) {
    const float* tokens = (const float*)d_in[0];
    const int*   t      = (const int*)d_in[1];
    const float* Wg     = (const float*)d_in[2];
    const float* bg     = (const float*)d_in[3];
    float*       outp   = (float*)d_out;

    int* wsI = (int*)d_ws;
    const long long wsInts = (long long)(ws_size / 4);

    // layout: [0..15] counter | [16 ..) whi 128KB | wlo 128KB | flagList
    const int  WHALF   = 32768;                  // ints per bf16 half (64*1024 shorts)
    const long long listOff = 16 + 2LL * WHALF;  // = 65552 ints
    long long cap = wsInts - listOff;
    if (cap > 65536) cap = 65536;

    hipMemsetAsync(d_ws, 0, 64, stream);   // zero flag counter (capturable)

    if (cap >= 32768) {
        short* whi  = (short*)(wsI + 16);
        short* wlo  = (short*)(wsI + 16 + WHALF);
        int*   list = wsI + listOff;
        wsplit_kernel<<<dim3(32), dim3(256), 0, stream>>>(Wg, whi, wlo);
        router_kernel<<<dim3(65536 / 64), dim3(256), 0, stream>>>(
            tokens, t, bg, outp, wsI, list, (int)cap, whi, wlo);
        repair_kernel<<<dim3(256), dim3(256), 0, stream>>>(
            tokens, t, Wg, bg, outp, wsI, list, (int)cap);
    } else {
        long long cap2 = wsInts - 16;
        if (cap2 < 0) cap2 = 0;
        if (cap2 > 65536) cap2 = 65536;
        router_kernel_legacy<<<dim3(65536 / 64), dim3(256), 0, stream>>>(
            tokens, t, Wg, bg, outp, wsI, wsI + 16, (int)cap2);
        repair_kernel<<<dim3(256), dim3(256), 0, stream>>>(
            tokens, t, Wg, bg, outp, wsI, wsI + 16, (int)cap2);
    }
}

// Round 6
// 444.506 us; speedup vs baseline: 1.0088x; 1.0082x over previous
//
#include <hip/hip_runtime.h>
#include <hip/hip_bf16.h>

typedef __attribute__((ext_vector_type(8))) short short8;   // 8 x bf16 = 4 VGPRs
typedef __attribute__((ext_vector_type(4))) short sh4;      // 4 x bf16 = 8 bytes
typedef __attribute__((ext_vector_type(4))) float floatx4;  // MFMA C/D

// total ordering: larger value wins; tie -> smaller index wins (jax.lax.top_k)
__device__ __forceinline__ bool better(float va, int ia, float vb, int ib) {
    return (va > vb) || (va == vb && ia < ib);
}
__device__ __forceinline__ bool betterd(double va, int ia, double vb, int ib) {
    return (va > vb) || (va == vb && ia < ib);
}

__device__ __forceinline__ short bf16_rn(float f) {
    __hip_bfloat16 h = __float2bfloat16(f);   // round-to-nearest-even
    return *reinterpret_cast<short*>(&h);
}
__device__ __forceinline__ float bf16_up(short s) {
    return __uint_as_float(((unsigned)(unsigned short)s) << 16);
}

// split 8 fp32 into bf16 hi + bf16 lo fragments (a ~= hi + lo)
__device__ __forceinline__ void split8(float4 a, float4 b, short8& hi, short8& lo) {
    float v[8] = {a.x, a.y, a.z, a.w, b.x, b.y, b.z, b.w};
    #pragma unroll
    for (int i = 0; i < 8; ++i) {
        short h = bf16_rn(v[i]);
        hi[i] = h;
        lo[i] = bf16_rn(v[i] - bf16_up(h));
    }
}

#define MFMA(A, B, C) __builtin_amdgcn_mfma_f32_16x16x32_bf16((A), (B), (C), 0, 0, 0)

// async global -> LDS, 16B per lane.  LDS dest = wave-uniform base + lane*16.
__device__ __forceinline__ void gload16(const void* g, void* l) {
    __builtin_amdgcn_global_load_lds(
        (const __attribute__((address_space(1))) void*)g,
        (__attribute__((address_space(3))) void*)l,
        16, 0, 0);
}

// ---------------------------------------------------------------------------
// Prep: split W (64x1024 fp32) into bf16 hi/lo, PERMUTED so router staging and
// reads are both linear-in-lane.  Granule = 8 bf16 (16B).  Layout:
//   whi[c][g][q][e] : chunk c (32 k-floats), expert group g (experts 16g+e),
//                     k-octet q (k = 32c + 8q .. +7), e in 0..15.
//   idx = c*256 + g*64 + q*16 + e   (8192 granules, 128 KB per half)
// ---------------------------------------------------------------------------
__global__ __launch_bounds__(256)
void wsplit_kernel(const float* __restrict__ Wg,
                   short* __restrict__ whi,
                   short* __restrict__ wlo)
{
    const int idx = blockIdx.x * 256 + threadIdx.x;   // 32 blocks -> 8192 granules
    const int c = idx >> 8;
    const int g = (idx >> 6) & 3;
    const int q = (idx >> 4) & 3;
    const int e = idx & 15;
    const float* src = Wg + (size_t)(g * 16 + e) * 1024 + c * 32 + q * 8;
    float4 v0 = reinterpret_cast<const float4*>(src)[0];
    float4 v1 = reinterpret_cast<const float4*>(src)[1];
    short8 hi, lo;
    split8(v0, v1, hi, lo);
    reinterpret_cast<short8*>(whi)[idx] = hi;
    reinterpret_cast<short8*>(wlo)[idx] = lo;
}

// ---------------------------------------------------------------------------
// Main router — quarter-burst A loads with a SAFE wait schedule.
//   A (wave-private): one quarter-row burst per 8 chunks — 16 back-to-back
//     dwordx4 loads (1 KB contiguous per token row) into aq[8][2], consumed
//     with compile-time indices only.  Next burst issues in the shadow of the
//     quarter's last chunk.
//   W (block-shared): pre-split bf16 hi/lo via global_load_lds, 2 x 8KB LDS
//     double buffer, conflict-free linear layout; 2 DMA per wave per chunk.
//   Wait schedule (no mixed-type counting):
//     - quarter-head chunks and the final chunk: vmcnt(0) FULL DRAIN (A burst
//       + both W prefetches unconditionally complete; 5 drains per kernel).
//     - all other chunk heads: vmcnt(2) over a PURE-W queue (exactly the
//       pattern verified passing in earlier rounds).
// Numerics bitwise identical to all passing rounds: same split8 values,
// same MFMA order.
// ---------------------------------------------------------------------------
__global__ __launch_bounds__(256, 2)
void router_kernel(const float* __restrict__ tokens,
                   const int* __restrict__ tarr,
                   const float* __restrict__ bg,
                   float* __restrict__ out,
                   int* __restrict__ flagCount,
                   int* __restrict__ flagList,
                   int listCap,
                   const short* __restrict__ whi,
                   const short* __restrict__ wlo)
{
    __shared__ __align__(16) float gtile[64 * 64];   // 16 KB gate tile
    __shared__ __align__(16) char  wbuf[2][8192];    // 16 KB W dbuf (Whi | Wlo)

    const int lane = threadIdx.x & 63;
    const int wave = threadIdx.x >> 6;
    const int c16  = lane & 15;   // token-within-wave (A row) / expert-within-group
    const int quad = lane >> 4;   // k-octet selector

    const int tokenBase = blockIdx.x * 64;
    const int token     = tokenBase + wave * 16 + c16;

    // A fragment source: floats [token*1024 + c*32 + quad*8 .. +7]
    const float4* ap = reinterpret_cast<const float4*>(tokens) + (size_t)token * 256 + quad * 2;

    // W staging source (contiguous 1KB per wave per half per chunk)
    const char* hS = (const char*)whi + wave * 1024 + (size_t)lane * 16;
    const char* lS = (const char*)wlo + wave * 1024 + (size_t)lane * 16;

    const int wRd = lane * 16;   // lane's W read offset (q=quad, e=c16 granule)

    floatx4 acc0 = {0.f, 0.f, 0.f, 0.f};
    floatx4 acc1 = acc0, acc2 = acc0, acc3 = acc0;

#define STAGE_W(c, wb)  do {                                              \
        gload16(hS + (size_t)(c) * 4096, (wb) + wave * 1024);             \
        gload16(lS + (size_t)(c) * 4096, (wb) + 4096 + wave * 1024);      \
    } while (0)

#define COMPUTE(wb, A0, A1)  do {                                         \
        const char* bW = (wb);                                            \
        short8 h0 = *(const short8*)(bW +    0 + wRd);                    \
        short8 h1 = *(const short8*)(bW + 1024 + wRd);                    \
        short8 h2 = *(const short8*)(bW + 2048 + wRd);                    \
        short8 h3 = *(const short8*)(bW + 3072 + wRd);                    \
        short8 l0 = *(const short8*)(bW + 4096 + wRd);                    \
        short8 l1 = *(const short8*)(bW + 5120 + wRd);                    \
        short8 l2 = *(const short8*)(bW + 6144 + wRd);                    \
        short8 l3 = *(const short8*)(bW + 7168 + wRd);                    \
        short8 ahi, alo;                                                  \
        split8((A0), (A1), ahi, alo);                                     \
        acc0 = MFMA(ahi, h0, acc0); acc0 = MFMA(alo, h0, acc0); acc0 = MFMA(ahi, l0, acc0); \
        acc1 = MFMA(ahi, h1, acc1); acc1 = MFMA(alo, h1, acc1); acc1 = MFMA(ahi, l1, acc1); \
        acc2 = MFMA(ahi, h2, acc2); acc2 = MFMA(alo, h2, acc2); acc2 = MFMA(ahi, l2, acc2); \
        acc3 = MFMA(ahi, h3, acc3); acc3 = MFMA(alo, h3, acc3); acc3 = MFMA(ahi, l3, acc3); \
    } while (0)

    float4 aq[8][2];   // quarter of A; only compile-time-unrolled indexing

    // prologue: A quarter 0 burst + W chunks 0,1 in flight
    #pragma unroll
    for (int j = 0; j < 8; ++j) {
        aq[j][0] = ap[j * 8];
        aq[j][1] = ap[j * 8 + 1];
    }
    STAGE_W(0, wbuf[0]);
    STAGE_W(1, wbuf[1]);

    #pragma unroll
    for (int q = 0; q < 4; ++q) {
        #pragma unroll
        for (int i = 0; i < 8; ++i) {
            const int c = q * 8 + i;
            if (i == 0 || c == 31) {
                // quarter head / final chunk: FULL DRAIN (A burst + W landed)
                asm volatile("s_waitcnt vmcnt(0)" ::: "memory");
            } else {
                // mid-quarter: pure-W queue [W_c, W_{c+1}] -> complete W_c
                asm volatile("s_waitcnt vmcnt(2)" ::: "memory");
            }
            __builtin_amdgcn_s_barrier();
            asm volatile("" ::: "memory");

            COMPUTE(wbuf[i & 1], aq[i][0], aq[i][1]);

            __builtin_amdgcn_s_barrier();
            asm volatile("" ::: "memory");

            if (c < 30) STAGE_W(c + 2, wbuf[i & 1]);
            if (i == 7 && q < 3) {
                // next quarter's A burst (16 back-to-back loads, 1KB/row)
                #pragma unroll
                for (int j = 0; j < 8; ++j) {
                    aq[j][0] = ap[(q + 1) * 64 + j * 8];
                    aq[j][1] = ap[(q + 1) * 64 + j * 8 + 1];
                }
            }
        }
    }

#undef STAGE_W
#undef COMPUTE

    const float b0f = bg[c16 +  0];
    const float b1f = bg[c16 + 16];
    const float b2f = bg[c16 + 32];
    const float b3f = bg[c16 + 48];

    const float tb  = (float)tarr[tokenBase >> 12];   // 4096 tokens per batch
    const float cap = 0.5f + 1.1f * (tb / 1000.0f);

    const float A1 = 0.85f;            // 1 - alpha, alpha = 0.15
    const float A2 = 0.15f / 64.0f;    // alpha / E

    #pragma unroll
    for (int rr = 0; rr < 4; ++rr) {
        float l0 = acc0[rr] + b0f;
        float l1 = acc1[rr] + b1f;
        float l2 = acc2[rr] + b2f;
        float l3 = acc3[rr] + b3f;

        // --- softmax over 64 experts (16-lane group x 4 local) ---
        float mx = fmaxf(fmaxf(l0, l1), fmaxf(l2, l3));
        #pragma unroll
        for (int off = 8; off >= 1; off >>= 1)
            mx = fmaxf(mx, __shfl_xor(mx, off));

        float e0 = expf(l0 - mx), e1 = expf(l1 - mx);
        float e2 = expf(l2 - mx), e3 = expf(l3 - mx);
        float s = e0 + e1 + e2 + e3;
        #pragma unroll
        for (int off = 8; off >= 1; off >>= 1)
            s += __shfl_xor(s, off);
        float inv = 1.0f / s;

        // --- routing floor ---
        float p0 = A1 * (e0 * inv) + A2;
        float p1 = A1 * (e1 * inv) + A2;
        float p2 = A1 * (e2 * inv) + A2;
        float p3 = A1 * (e3 * inv) + A2;

        // --- hard cap with excess redistribution ---
        float x0 = fmaxf(p0 - cap, 0.f), x1 = fmaxf(p1 - cap, 0.f);
        float x2 = fmaxf(p2 - cap, 0.f), x3 = fmaxf(p3 - cap, 0.f);
        float m0 = p0 - x0, m1 = p1 - x1, m2 = p2 - x2, m3 = p3 - x3;
        float h0 = fmaxf(cap - m0, 0.f), h1 = fmaxf(cap - m1, 0.f);
        float h2 = fmaxf(cap - m2, 0.f), h3 = fmaxf(cap - m3, 0.f);
        float sx = x0 + x1 + x2 + x3;
        float sh = h0 + h1 + h2 + h3;
        #pragma unroll
        for (int off = 8; off >= 1; off >>= 1) {
            sx += __shfl_xor(sx, off);
            sh += __shfl_xor(sh, off);
        }
        sh = fmaxf(sh, 1e-8f);
        float sc = sx / sh;
        float c0 = m0 + sc * h0;
        float c1 = m1 + sc * h1;
        float c2 = m2 + sc * h2;
        float c3 = m3 + sc * h3;

        // --- top-2 (value desc, tie -> smaller expert index) ---
        const int iA = c16, iB = c16 + 16, iC = c16 + 32, iD = c16 + 48;
        float v1, v2; int j1, j2;
        if (better(c0, iA, c1, iB)) { v1 = c0; j1 = iA; v2 = c1; j2 = iB; }
        else                        { v1 = c1; j1 = iB; v2 = c0; j2 = iA; }
        if (better(c2, iC, v1, j1))      { v2 = v1; j2 = j1; v1 = c2; j1 = iC; }
        else if (better(c2, iC, v2, j2)) { v2 = c2; j2 = iC; }
        if (better(c3, iD, v1, j1))      { v2 = v1; j2 = j1; v1 = c3; j1 = iD; }
        else if (better(c3, iD, v2, j2)) { v2 = c3; j2 = iD; }

        #pragma unroll
        for (int off = 1; off < 16; off <<= 1) {
            float w1 = __shfl_xor(v1, off); int k1 = __shfl_xor(j1, off);
            float w2 = __shfl_xor(v2, off); int k2 = __shfl_xor(j2, off);
            if (better(w1, k1, v1, j1)) {
                if (better(v1, j1, w2, k2)) { v2 = v1; j2 = j1; }
                else                        { v2 = w2; j2 = k2; }
                v1 = w1; j1 = k1;
            } else if (better(w1, k1, v2, j2)) {
                v2 = w1; j2 = k1;
            }
        }

        float g0 = (iA == j1 || iA == j2) ? c0 : 0.f;
        float g1 = (iB == j1 || iB == j2) ? c1 : 0.f;
        float g2 = (iC == j1 || iC == j2) ? c2 : 0.f;
        float g3 = (iD == j1 || iD == j2) ? c3 : 0.f;

        // --- rank2 vs rank3 margin; flag uncertain tokens for fp64 repair ---
        float t0 = (iA == j1 || iA == j2) ? -3.0e38f : c0;
        float t1 = (iB == j1 || iB == j2) ? -3.0e38f : c1;
        float t2 = (iC == j1 || iC == j2) ? -3.0e38f : c2;
        float t3 = (iD == j1 || iD == j2) ? -3.0e38f : c3;
        float m3v = fmaxf(fmaxf(t0, t1), fmaxf(t2, t3));
        #pragma unroll
        for (int off = 8; off >= 1; off >>= 1)
            m3v = fmaxf(m3v, __shfl_xor(m3v, off));

        const int tl = wave * 16 + quad * 4 + rr;   // token within block
        bool flag = ((v2 - m3v) < 1e-4f) || (sx > 0.0f);
        if (flag && c16 == 0) {
            int pos = atomicAdd(flagCount, 1);
            if (pos < listCap) flagList[pos] = tokenBase + tl;
        }

        gtile[tl * 64 + iA] = g0;
        gtile[tl * 64 + iB] = g1;
        gtile[tl * 64 + iC] = g2;
        gtile[tl * 64 + iD] = g3;
    }

    __syncthreads();

    const uint4* src = reinterpret_cast<const uint4*>(gtile);
    uint4* dst = reinterpret_cast<uint4*>(out + (size_t)tokenBase * 64);
    dst[threadIdx.x]       = src[threadIdx.x];
    dst[threadIdx.x + 256] = src[threadIdx.x + 256];
    dst[threadIdx.x + 512] = src[threadIdx.x + 512];
    dst[threadIdx.x + 768] = src[threadIdx.x + 768];
}

// ---------------------------------------------------------------------------
// Legacy router (inline W split) — fallback when workspace is too small for
// the pre-split W area.  Identical to the originally verified kernel.
// ---------------------------------------------------------------------------
__global__ __launch_bounds__(256, 4)
void router_kernel_legacy(const float* __restrict__ tokens,
                          const int* __restrict__ tarr,
                          const float* __restrict__ Wg,
                          const float* __restrict__ bg,
                          float* __restrict__ out,
                          int* __restrict__ flagCount,
                          int* __restrict__ flagList,
                          int listCap)
{
    __shared__ __align__(16) float gtile[64 * 64];

    const int lane = threadIdx.x & 63;
    const int wave = threadIdx.x >> 6;
    const int c16  = lane & 15;
    const int quad = lane >> 4;

    const int tokenBase = blockIdx.x * 64;
    const int token     = tokenBase + wave * 16 + c16;

    const float4* ap = reinterpret_cast<const float4*>(tokens) + (size_t)token * 256 + quad * 2;
    const float4* wp0 = reinterpret_cast<const float4*>(Wg) + (size_t)(c16 +  0) * 256 + quad * 2;
    const float4* wp1 = reinterpret_cast<const float4*>(Wg) + (size_t)(c16 + 16) * 256 + quad * 2;
    const float4* wp2 = reinterpret_cast<const float4*>(Wg) + (size_t)(c16 + 32) * 256 + quad * 2;
    const float4* wp3 = reinterpret_cast<const float4*>(Wg) + (size_t)(c16 + 48) * 256 + quad * 2;

    floatx4 acc0 = {0.f, 0.f, 0.f, 0.f};
    floatx4 acc1 = acc0, acc2 = acc0, acc3 = acc0;

    for (int kb = 0; kb < 32; ++kb) {
        short8 ahi, alo;
        split8(ap[kb * 8], ap[kb * 8 + 1], ahi, alo);
        {
            short8 whi, wlo;
            split8(wp0[kb * 8], wp0[kb * 8 + 1], whi, wlo);
            acc0 = MFMA(ahi, whi, acc0);
            acc0 = MFMA(alo, whi, acc0);
            acc0 = MFMA(ahi, wlo, acc0);
        }
        {
            short8 whi, wlo;
            split8(wp1[kb * 8], wp1[kb * 8 + 1], whi, wlo);
            acc1 = MFMA(ahi, whi, acc1);
            acc1 = MFMA(alo, whi, acc1);
            acc1 = MFMA(ahi, wlo, acc1);
        }
        {
            short8 whi, wlo;
            split8(wp2[kb * 8], wp2[kb * 8 + 1], whi, wlo);
            acc2 = MFMA(ahi, whi, acc2);
            acc2 = MFMA(alo, whi, acc2);
            acc2 = MFMA(ahi, wlo, acc2);
        }
        {
            short8 whi, wlo;
            split8(wp3[kb * 8], wp3[kb * 8 + 1], whi, wlo);
            acc3 = MFMA(ahi, whi, acc3);
            acc3 = MFMA(alo, whi, acc3);
            acc3 = MFMA(ahi, wlo, acc3);
        }
    }

    const float b0f = bg[c16 +  0];
    const float b1f = bg[c16 + 16];
    const float b2f = bg[c16 + 32];
    const float b3f = bg[c16 + 48];

    const float tb  = (float)tarr[tokenBase >> 12];
    const float cap = 0.5f + 1.1f * (tb / 1000.0f);

    const float A1 = 0.85f;
    const float A2 = 0.15f / 64.0f;

    #pragma unroll
    for (int r = 0; r < 4; ++r) {
        float l0 = acc0[r] + b0f;
        float l1 = acc1[r] + b1f;
        float l2 = acc2[r] + b2f;
        float l3 = acc3[r] + b3f;

        float mx = fmaxf(fmaxf(l0, l1), fmaxf(l2, l3));
        #pragma unroll
        for (int off = 8; off >= 1; off >>= 1)
            mx = fmaxf(mx, __shfl_xor(mx, off));

        float e0 = expf(l0 - mx), e1 = expf(l1 - mx);
        float e2 = expf(l2 - mx), e3 = expf(l3 - mx);
        float s = e0 + e1 + e2 + e3;
        #pragma unroll
        for (int off = 8; off >= 1; off >>= 1)
            s += __shfl_xor(s, off);
        float inv = 1.0f / s;

        float p0 = A1 * (e0 * inv) + A2;
        float p1 = A1 * (e1 * inv) + A2;
        float p2 = A1 * (e2 * inv) + A2;
        float p3 = A1 * (e3 * inv) + A2;

        float x0 = fmaxf(p0 - cap, 0.f), x1 = fmaxf(p1 - cap, 0.f);
        float x2 = fmaxf(p2 - cap, 0.f), x3 = fmaxf(p3 - cap, 0.f);
        float m0 = p0 - x0, m1 = p1 - x1, m2 = p2 - x2, m3 = p3 - x3;
        float h0 = fmaxf(cap - m0, 0.f), h1 = fmaxf(cap - m1, 0.f);
        float h2 = fmaxf(cap - m2, 0.f), h3 = fmaxf(cap - m3, 0.f);
        float sx = x0 + x1 + x2 + x3;
        float sh = h0 + h1 + h2 + h3;
        #pragma unroll
        for (int off = 8; off >= 1; off >>= 1) {
            sx += __shfl_xor(sx, off);
            sh += __shfl_xor(sh, off);
        }
        sh = fmaxf(sh, 1e-8f);
        float sc = sx / sh;
        float c0 = m0 + sc * h0;
        float c1 = m1 + sc * h1;
        float c2 = m2 + sc * h2;
        float c3 = m3 + sc * h3;

        const int iA = c16, iB = c16 + 16, iC = c16 + 32, iD = c16 + 48;
        float v1, v2; int j1, j2;
        if (better(c0, iA, c1, iB)) { v1 = c0; j1 = iA; v2 = c1; j2 = iB; }
        else                        { v1 = c1; j1 = iB; v2 = c0; j2 = iA; }
        if (better(c2, iC, v1, j1))      { v2 = v1; j2 = j1; v1 = c2; j1 = iC; }
        else if (better(c2, iC, v2, j2)) { v2 = c2; j2 = iC; }
        if (better(c3, iD, v1, j1))      { v2 = v1; j2 = j1; v1 = c3; j1 = iD; }
        else if (better(c3, iD, v2, j2)) { v2 = c3; j2 = iD; }

        #pragma unroll
        for (int off = 1; off < 16; off <<= 1) {
            float w1 = __shfl_xor(v1, off); int k1 = __shfl_xor(j1, off);
            float w2 = __shfl_xor(v2, off); int k2 = __shfl_xor(j2, off);
            if (better(w1, k1, v1, j1)) {
                if (better(v1, j1, w2, k2)) { v2 = v1; j2 = j1; }
                else                        { v2 = w2; j2 = k2; }
                v1 = w1; j1 = k1;
            } else if (better(w1, k1, v2, j2)) {
                v2 = w1; j2 = k1;
            }
        }

        float g0 = (iA == j1 || iA == j2) ? c0 : 0.f;
        float g1 = (iB == j1 || iB == j2) ? c1 : 0.f;
        float g2 = (iC == j1 || iC == j2) ? c2 : 0.f;
        float g3 = (iD == j1 || iD == j2) ? c3 : 0.f;

        float t0 = (iA == j1 || iA == j2) ? -3.0e38f : c0;
        float t1 = (iB == j1 || iB == j2) ? -3.0e38f : c1;
        float t2 = (iC == j1 || iC == j2) ? -3.0e38f : c2;
        float t3 = (iD == j1 || iD == j2) ? -3.0e38f : c3;
        float m3v = fmaxf(fmaxf(t0, t1), fmaxf(t2, t3));
        #pragma unroll
        for (int off = 8; off >= 1; off >>= 1)
            m3v = fmaxf(m3v, __shfl_xor(m3v, off));

        const int tl = wave * 16 + quad * 4 + r;
        bool flag = ((v2 - m3v) < 1e-4f) || (sx > 0.0f);
        if (flag && c16 == 0) {
            int pos = atomicAdd(flagCount, 1);
            if (pos < listCap) flagList[pos] = tokenBase + tl;
        }

        gtile[tl * 64 + iA] = g0;
        gtile[tl * 64 + iB] = g1;
        gtile[tl * 64 + iC] = g2;
        gtile[tl * 64 + iD] = g3;
    }

    __syncthreads();

    const uint4* src = reinterpret_cast<const uint4*>(gtile);
    uint4* dst = reinterpret_cast<uint4*>(out + (size_t)tokenBase * 64);
    dst[threadIdx.x]       = src[threadIdx.x];
    dst[threadIdx.x + 256] = src[threadIdx.x + 256];
    dst[threadIdx.x + 512] = src[threadIdx.x + 512];
    dst[threadIdx.x + 768] = src[threadIdx.x + 768];
}

// ---------------------------------------------------------------------------
// fp64 exact recompute of flagged tokens — batched: 8 tokens share one W pass.
// ---------------------------------------------------------------------------
__global__ __launch_bounds__(256)
void repair_kernel(const float* __restrict__ tokens,
                   const int* __restrict__ tarr,
                   const float* __restrict__ Wg,
                   const float* __restrict__ bg,
                   float* __restrict__ out,
                   const int* __restrict__ cnt,
                   const int* __restrict__ list,
                   int listCap)
{
    __shared__ __align__(16) float atile[8][1024];   // 32 KB
    __shared__ double red[256];                      //  2 KB
    int count = cnt[0];
    if (count > listCap) count = listCap;

    const int e    = threadIdx.x & 63;   // expert
    const int part = threadIdx.x >> 6;   // k-quarter

    for (int base = blockIdx.x * 8; base < count; base += gridDim.x * 8) {
        const int n = min(8, count - base);

        #pragma unroll
        for (int t = 0; t < 8; ++t) {
            if (t < n) {
                const float4* src =
                    reinterpret_cast<const float4*>(tokens + (size_t)list[base + t] * 1024);
                reinterpret_cast<float4*>(atile[t])[threadIdx.x] = src[threadIdx.x];
            }
        }
        __syncthreads();

        double acc0 = 0.0, acc1 = 0.0, acc2 = 0.0, acc3 = 0.0;
        double acc4 = 0.0, acc5 = 0.0, acc6 = 0.0, acc7 = 0.0;
        const float* wrow = Wg + (size_t)e * 1024 + part * 256;
        const int ko = part * 256;
        for (int k = 0; k < 256; k += 4) {
            float4 wv = *reinterpret_cast<const float4*>(wrow + k);
            const double w0 = (double)wv.x, w1 = (double)wv.y;
            const double w2 = (double)wv.z, w3 = (double)wv.w;
            #define ACC(T, A)                                                   \
                A = fma((double)atile[T][ko + k    ], w0, A);                    \
                A = fma((double)atile[T][ko + k + 1], w1, A);                    \
                A = fma((double)atile[T][ko + k + 2], w2, A);                    \
                A = fma((double)atile[T][ko + k + 3], w3, A);
            ACC(0, acc0) ACC(1, acc1) ACC(2, acc2) ACC(3, acc3)
            ACC(4, acc4) ACC(5, acc5) ACC(6, acc6) ACC(7, acc7)
            #undef ACC
        }

        #pragma unroll
        for (int t = 0; t < 8; ++t) {
            if (t >= n) break;
            double accT = (t == 0) ? acc0 : (t == 1) ? acc1 : (t == 2) ? acc2 :
                          (t == 3) ? acc3 : (t == 4) ? acc4 : (t == 5) ? acc5 :
                          (t == 6) ? acc6 : acc7;
            red[threadIdx.x] = accT;
            __syncthreads();

            if (threadIdx.x < 64) {
                const int token = list[base + t];
                double l = ((red[e] + red[64 + e]) + (red[128 + e] + red[192 + e]))
                         + (double)bg[e];

                double mxv = l;
                #pragma unroll
                for (int off = 32; off >= 1; off >>= 1)
                    mxv = fmax(mxv, __shfl_xor(mxv, off));
                double ex = exp(l - mxv);
                double s = ex;
                #pragma unroll
                for (int off = 32; off >= 1; off >>= 1)
                    s += __shfl_xor(s, off);

                const double alpha = 0.15;
                double p = (1.0 - alpha) * (ex / s) + alpha / 64.0;

                double tb  = (double)tarr[token >> 12];
                double capv = 0.5 + (0.6 + 0.5) * (tb / 1000.0);
                double x = fmax(p - capv, 0.0);
                double m = p - x;
                double h = fmax(capv - m, 0.0);
                double sx = x, sh = h;
                #pragma unroll
                for (int off = 32; off >= 1; off >>= 1) {
                    sx += __shfl_xor(sx, off);
                    sh += __shfl_xor(sh, off);
                }
                sh = fmax(sh, 1e-8);
                double c = m + (sx / sh) * h;

                double v1 = c, v2 = -1.0e300;
                int j1 = e, j2 = 127;
                #pragma unroll
                for (int off = 1; off < 64; off <<= 1) {
                    double w1 = __shfl_xor(v1, off); int k1 = __shfl_xor(j1, off);
                    double w2 = __shfl_xor(v2, off); int k2 = __shfl_xor(j2, off);
                    if (betterd(w1, k1, v1, j1)) {
                        if (betterd(v1, j1, w2, k2)) { v2 = v1; j2 = j1; }
                        else                         { v2 = w2; j2 = k2; }
                        v1 = w1; j1 = k1;
                    } else if (betterd(w1, k1, v2, j2)) {
                        v2 = w1; j2 = k1;
                    }
                }

                float g = (e == j1 || e == j2) ? (float)c : 0.0f;
                out[(size_t)token * 64 + e] = g;
            }
            __syncthreads();
        }
    }
}

extern "C" void kernel_launch(void* const* d_in, const int* in_sizes, int n_in,
                              void* d_out, int out_size, void* d_ws, size_t ws_size,
                              hipStream_t stream) {
    const float* tokens = (const float*)d_in[0];
    const int*   t      = (const int*)d_in[1];
    const float* Wg     = (const float*)d_in[2];
    const float* bg     = (const float*)d_in[3];
    float*       outp   = (float*)d_out;

    int* wsI = (int*)d_ws;
    const long long wsInts = (long long)(ws_size / 4);

    // layout: [0..15] counter | [16 ..) whi 128KB | wlo 128KB | flagList
    const int  WHALF   = 32768;                  // ints per bf16 half (64*1024 shorts)
    const long long listOff = 16 + 2LL * WHALF;  // = 65552 ints
    long long cap = wsInts - listOff;
    if (cap > 65536) cap = 65536;

    hipMemsetAsync(d_ws, 0, 64, stream);   // zero flag counter (capturable)

    if (cap >= 32768) {
        short* whi  = (short*)(wsI + 16);
        short* wlo  = (short*)(wsI + 16 + WHALF);
        int*   list = wsI + listOff;
        wsplit_kernel<<<dim3(32), dim3(256), 0, stream>>>(Wg, whi, wlo);
        router_kernel<<<dim3(65536 / 64), dim3(256), 0, stream>>>(
            tokens, t, bg, outp, wsI, list, (int)cap, whi, wlo);
        repair_kernel<<<dim3(256), dim3(256), 0, stream>>>(
            tokens, t, Wg, bg, outp, wsI, list, (int)cap);
    } else {
        long long cap2 = wsInts - 16;
        if (cap2 < 0) cap2 = 0;
        if (cap2 > 65536) cap2 = 65536;
        router_kernel_legacy<<<dim3(65536 / 64), dim3(256), 0, stream>>>(
            tokens, t, Wg, bg, outp, wsI, wsI + 16, (int)cap2);
        repair_kernel<<<dim3(256), dim3(256), 0, stream>>>(
            tokens, t, Wg, bg, outp, wsI, wsI + 16, (int)cap2);
    }
}